// Round 1
// baseline (611.243 us; speedup 1.0000x reference)
//
#include <hip/hip_runtime.h>

#define N_NODES 8192
#define N_EDGES 262144
#define NFEAT 200
#define NHID 128

// ---------------- GEMM: C[nrows,128] = A[nrows,K] @ W[128,K]^T ----------------
template<int K>
__global__ __launch_bounds__(128) void gemm_rows(const float* __restrict__ A,
                                                 const float* __restrict__ W,
                                                 float* __restrict__ C,
                                                 int nrows) {
    __shared__ float a_s[8 * K];
    int row0 = blockIdx.x * 8;
    const float* Ab = A + (size_t)row0 * K;
    for (int idx = threadIdx.x; idx < 8 * K; idx += 128) a_s[idx] = Ab[idx];
    __syncthreads();
    int j = threadIdx.x;
    float acc[8] = {0.f, 0.f, 0.f, 0.f, 0.f, 0.f, 0.f, 0.f};
    const float4* W4 = (const float4*)(W + (size_t)j * K);
    for (int k4 = 0; k4 < K / 4; ++k4) {
        float4 w = W4[k4];
        int k = k4 * 4;
        #pragma unroll
        for (int r = 0; r < 8; ++r) {
            const float* ar = a_s + r * K + k;
            acc[r] += ar[0] * w.x + ar[1] * w.y + ar[2] * w.z + ar[3] * w.w;
        }
    }
    #pragma unroll
    for (int r = 0; r < 8; ++r) C[(size_t)(row0 + r) * 128 + j] = acc[r];
}

// ---------------- Edge aggregate: out[dst] += w * H[src], 128 dims ----------------
__global__ __launch_bounds__(256) void agg_edges(const int* __restrict__ ei,
                                                 const float* __restrict__ ew,
                                                 const float* __restrict__ H,
                                                 float* __restrict__ out, int E) {
    const int* src = ei;
    const int* dst = ei + E;
    int wave = (blockIdx.x * blockDim.x + threadIdx.x) >> 6;
    int lane = threadIdx.x & 63;
    int nw = (gridDim.x * blockDim.x) >> 6;
    for (int e = wave; e < E; e += nw) {
        int s = src[e], d = dst[e];
        float w = ew[e];
        float2 v = *(const float2*)(H + (size_t)s * 128 + lane * 2);
        float* o = out + (size_t)d * 128 + lane * 2;
        atomicAdd(o, v.x * w);
        atomicAdd(o + 1, v.y * w);
    }
}

// ---------------- LayerNorm(+bias) + ReLU, in place, one wave per 128-dim row ----------------
__global__ __launch_bounds__(256) void ln_relu_kernel(float* __restrict__ H,
                                                      const float* __restrict__ bias,
                                                      const float* __restrict__ g,
                                                      const float* __restrict__ b,
                                                      int nrows) {
    int wave = (blockIdx.x * blockDim.x + threadIdx.x) >> 6;
    int lane = threadIdx.x & 63;
    if (wave >= nrows) return;
    float2 v = *(float2*)(H + (size_t)wave * 128 + lane * 2);
    float2 bs = *(const float2*)(bias + lane * 2);
    v.x += bs.x; v.y += bs.y;
    float s = v.x + v.y;
    float ss = v.x * v.x + v.y * v.y;
    for (int off = 32; off; off >>= 1) {
        s += __shfl_xor(s, off, 64);
        ss += __shfl_xor(ss, off, 64);
    }
    float mu = s * (1.f / 128.f);
    float var = ss * (1.f / 128.f) - mu * mu;
    float rs = rsqrtf(var + 1e-5f);
    float2 gg = *(const float2*)(g + lane * 2);
    float2 bb = *(const float2*)(b + lane * 2);
    float y0 = fmaxf((v.x - mu) * rs * gg.x + bb.x, 0.f);
    float y1 = fmaxf((v.y - mu) * rs * gg.y + bb.y, 0.f);
    *(float2*)(H + (size_t)wave * 128 + lane * 2) = make_float2(y0, y1);
}

// ---------------- pool0: logits + gumbel argmax -> c0, and xc0 cluster sums ----------------
__global__ __launch_bounds__(256) void pool0_kernel(const float* __restrict__ latent,
                                                    const float* __restrict__ pW,
                                                    const float* __restrict__ pb,
                                                    const float* __restrict__ gum,
                                                    int* __restrict__ c0,
                                                    float* __restrict__ xc0,
                                                    int nrows) {
    __shared__ float Ws[10 * 128];
    __shared__ float bs[10];
    for (int i = threadIdx.x; i < 1280; i += 256) Ws[i] = pW[i];
    if (threadIdx.x < 10) bs[threadIdx.x] = pb[threadIdx.x];
    __syncthreads();
    int wid = threadIdx.x >> 6, lane = threadIdx.x & 63;
    int row = blockIdx.x * 4 + wid;
    if (row >= nrows) return;
    float2 x = *(const float2*)(latent + (size_t)row * 128 + lane * 2);
    float p[10];
    #pragma unroll
    for (int k = 0; k < 10; ++k)
        p[k] = x.x * Ws[k * 128 + lane * 2] + x.y * Ws[k * 128 + lane * 2 + 1];
    for (int off = 32; off; off >>= 1) {
        #pragma unroll
        for (int k = 0; k < 10; ++k) p[k] += __shfl_xor(p[k], off, 64);
    }
    int best = 0;
    float bv = p[0] + bs[0] + gum[row * 10];
    #pragma unroll
    for (int k = 1; k < 10; ++k) {
        float z = p[k] + bs[k] + gum[row * 10 + k];
        if (z > bv) { bv = z; best = k; }   // strict > : first max wins (jnp.argmax)
    }
    if (lane == 0) c0[row] = best;
    atomicAdd(&xc0[best * 128 + lane * 2], x.x);
    atomicAdd(&xc0[best * 128 + lane * 2 + 1], x.y);
}

// ---------------- A0[a,b] = sum_e w_e [c0[src]=a][c0[dst]=b] ----------------
__global__ __launch_bounds__(256) void adj_pool_kernel(const int* __restrict__ ei,
                                                       const float* __restrict__ ew,
                                                       const int* __restrict__ c0,
                                                       float* __restrict__ A0, int E) {
    __shared__ float As[100];
    for (int i = threadIdx.x; i < 100; i += 256) As[i] = 0.f;
    __syncthreads();
    const int* src = ei;
    const int* dst = ei + E;
    for (int e = blockIdx.x * blockDim.x + threadIdx.x; e < E; e += gridDim.x * blockDim.x) {
        int a = c0[src[e]], b = c0[dst[e]];
        atomicAdd(&As[a * 10 + b], ew[e]);
    }
    __syncthreads();
    for (int i = threadIdx.x; i < 100; i += 256) atomicAdd(&A0[i], As[i]);
}

// ---------------- single-block: levels 0/1 coarse math -> tbl[10][16] ----------------
__global__ __launch_bounds__(256) void small_kernel(const float* __restrict__ xc0,
                                                    const float* __restrict__ A0,
                                                    const float* __restrict__ gum1,
                                                    const float* __restrict__ p1W,
                                                    const float* __restrict__ p1b,
                                                    const float* __restrict__ e0W,
                                                    const float* __restrict__ e0b,
                                                    const float* __restrict__ e1W,
                                                    const float* __restrict__ e1b,
                                                    const float* __restrict__ fcW,
                                                    const float* __restrict__ fcb,
                                                    float* __restrict__ tbl) {
    __shared__ float xc0n[10 * 128];
    __shared__ float adj0[100];
    __shared__ float m0[10 * 128];
    __shared__ float l1[10 * 128];
    __shared__ float xc1n[5 * 128];
    __shared__ float l2[5 * 128];
    __shared__ float A1[25];
    __shared__ int c1[10];
    __shared__ float red[4];

    int tid = threadIdx.x;
    int wid = tid >> 6, lane = tid & 63;

    // xc0 row-normalize
    for (int r = wid; r < 10; r += 4) {
        float2 v = *(const float2*)(xc0 + r * 128 + lane * 2);
        float ss = v.x * v.x + v.y * v.y;
        for (int off = 32; off; off >>= 1) ss += __shfl_xor(ss, off, 64);
        float sc = 1.f / fmaxf(sqrtf(ss), 1e-12f);
        xc0n[r * 128 + lane * 2] = v.x * sc;
        xc0n[r * 128 + lane * 2 + 1] = v.y * sc;
    }
    __syncthreads();
    // adj0 = A0 / (sum(A0) + 100*1e-8)
    if (tid == 0) {
        float s = 0.f;
        for (int i = 0; i < 100; ++i) s += A0[i];
        red[0] = s + 1e-6f;
    }
    __syncthreads();
    if (tid < 100) adj0[tid] = A0[tid] / red[0];
    __syncthreads();
    // m0 = adj0 @ xc0n
    for (int idx = tid; idx < 1280; idx += 256) {
        int r = idx >> 7, d = idx & 127;
        float acc = 0.f;
        #pragma unroll
        for (int a = 0; a < 10; ++a) acc += adj0[r * 10 + a] * xc0n[a * 128 + d];
        m0[idx] = acc;
    }
    __syncthreads();
    // l1 = relu(m0 @ e0W^T + e0b)
    for (int idx = tid; idx < 1280; idx += 256) {
        int r = idx >> 7, d = idx & 127;
        float acc = e0b[d];
        const float* wrow = e0W + d * 128;
        for (int k = 0; k < 128; ++k) acc += m0[r * 128 + k] * wrow[k];
        l1[idx] = fmaxf(acc, 0.f);
    }
    __syncthreads();
    // logits1 + gumbel1 argmax -> c1
    if (tid < 10) {
        int best = 0;
        float bv = -1e30f;
        for (int j = 0; j < 5; ++j) {
            float acc = p1b[j] + gum1[tid * 5 + j];
            const float* wrow = p1W + j * 128;
            for (int k = 0; k < 128; ++k) acc += l1[tid * 128 + k] * wrow[k];
            if (acc > bv) { bv = acc; best = j; }
        }
        c1[tid] = best;
    }
    __syncthreads();
    // xc1 = segsum(l1 by c1)
    for (int idx = tid; idx < 640; idx += 256) {
        int m = idx >> 7, d = idx & 127;
        float acc = 0.f;
        #pragma unroll
        for (int k = 0; k < 10; ++k)
            if (c1[k] == m) acc += l1[k * 128 + d];
        xc1n[idx] = acc;
    }
    __syncthreads();
    // normalize rows of xc1
    for (int r = wid; r < 5; r += 4) {
        float2 v = *(const float2*)(xc1n + r * 128 + lane * 2);
        float ss = v.x * v.x + v.y * v.y;
        for (int off = 32; off; off >>= 1) ss += __shfl_xor(ss, off, 64);
        float sc = 1.f / fmaxf(sqrtf(ss), 1e-12f);
        xc1n[r * 128 + lane * 2] = v.x * sc;
        xc1n[r * 128 + lane * 2 + 1] = v.y * sc;
    }
    __syncthreads();
    // A1[m,n] = sum_{a,b} adj0[a,b][c1[a]=m][c1[b]=n]
    if (tid < 25) {
        int m = tid / 5, n = tid % 5;
        float acc = 0.f;
        for (int a = 0; a < 10; ++a)
            for (int b = 0; b < 10; ++b)
                if (c1[a] == m && c1[b] == n) acc += adj0[a * 10 + b];
        A1[tid] = acc;
    }
    __syncthreads();
    if (tid == 0) {
        float s = 0.f;
        for (int i = 0; i < 25; ++i) s += A1[i];
        red[1] = s + 25e-8f;
    }
    __syncthreads();
    float den1 = red[1];
    // m1 = (A1/den1) @ xc1n   (reuse m0)
    for (int idx = tid; idx < 640; idx += 256) {
        int r = idx >> 7, d = idx & 127;
        float acc = 0.f;
        #pragma unroll
        for (int a = 0; a < 5; ++a) acc += A1[r * 5 + a] * xc1n[a * 128 + d];
        m0[idx] = acc / den1;
    }
    __syncthreads();
    // l2 = relu(m1 @ e1W^T + e1b)
    for (int idx = tid; idx < 640; idx += 256) {
        int r = idx >> 7, d = idx & 127;
        float acc = e1b[d];
        const float* wrow = e1W + d * 128;
        for (int k = 0; k < 128; ++k) acc += m0[r * 128 + k] * wrow[k];
        l2[idx] = fmaxf(acc, 0.f);
    }
    __syncthreads();
    // tbl[k][o] = fcb[o] + l1[k]·fcW[o,128:256] + l2[c1[k]]·fcW[o,256:384]
    for (int idx = tid; idx < 160; idx += 256) {
        int k = idx >> 4, o = idx & 15;
        float acc = fcb[o];
        const float* fB = fcW + o * 384 + 128;
        const float* fC = fcW + o * 384 + 256;
        const float* a1 = l1 + k * 128;
        const float* a2 = l2 + c1[k] * 128;
        for (int d = 0; d < 128; ++d) acc += a1[d] * fB[d] + a2[d] * fC[d];
        tbl[idx] = acc;
    }
}

// ---------------- out[i] = latent[i] @ fcA^T + tbl[c0[i]] ----------------
__global__ __launch_bounds__(256) void out_kernel(const float* __restrict__ latent,
                                                  const int* __restrict__ c0,
                                                  const float* __restrict__ tbl,
                                                  const float* __restrict__ fcW,
                                                  float* __restrict__ out, int nrows) {
    __shared__ float fA[16 * 128];
    __shared__ float ts[160];
    for (int i = threadIdx.x; i < 2048; i += 256) {
        int o = i >> 7, d = i & 127;
        fA[i] = fcW[o * 384 + d];
    }
    for (int i = threadIdx.x; i < 160; i += 256) ts[i] = tbl[i];
    __syncthreads();
    int wid = threadIdx.x >> 6, lane = threadIdx.x & 63;
    int row = blockIdx.x * 4 + wid;
    if (row >= nrows) return;
    float2 x = *(const float2*)(latent + (size_t)row * 128 + lane * 2);
    float p[16];
    #pragma unroll
    for (int o = 0; o < 16; ++o)
        p[o] = x.x * fA[o * 128 + lane * 2] + x.y * fA[o * 128 + lane * 2 + 1];
    for (int off = 32; off; off >>= 1) {
        #pragma unroll
        for (int o = 0; o < 16; ++o) p[o] += __shfl_xor(p[o], off, 64);
    }
    if (lane < 16) {
        int c = c0[row];
        out[(size_t)row * 16 + lane] = p[lane] + ts[c * 16 + lane];
    }
}

extern "C" void kernel_launch(void* const* d_in, const int* in_sizes, int n_in,
                              void* d_out, int out_size, void* d_ws, size_t ws_size,
                              hipStream_t stream) {
    const float* x    = (const float*)d_in[0];
    const int*   ei   = (const int*)d_in[1];
    const float* ew   = (const float*)d_in[2];
    const float* g0   = (const float*)d_in[3];
    const float* g1   = (const float*)d_in[4];
    const float* Wg1  = (const float*)d_in[5];
    const float* bg1  = (const float*)d_in[6];
    const float* ln1g = (const float*)d_in[7];
    const float* ln1b = (const float*)d_in[8];
    const float* Wg2  = (const float*)d_in[9];
    const float* bg2  = (const float*)d_in[10];
    const float* ln2g = (const float*)d_in[11];
    const float* ln2b = (const float*)d_in[12];
    const float* p0W  = (const float*)d_in[13];
    const float* p0b  = (const float*)d_in[14];
    const float* p1W  = (const float*)d_in[15];
    const float* p1b  = (const float*)d_in[16];
    const float* e0W  = (const float*)d_in[17];
    const float* e0b  = (const float*)d_in[18];
    const float* e1W  = (const float*)d_in[19];
    const float* e1b  = (const float*)d_in[20];
    const float* fcW  = (const float*)d_in[21];
    const float* fcb  = (const float*)d_in[22];
    float* out = (float*)d_out;

    float* ws   = (float*)d_ws;
    float* bufA = ws;                                   // N*128
    float* bufB = ws + (size_t)N_NODES * 128;           // N*128
    int*   c0   = (int*)(ws + (size_t)2 * N_NODES * 128);  // N ints
    float* xc0  = ws + (size_t)2 * N_NODES * 128 + N_NODES; // 1280
    float* A0   = xc0 + 1280;                           // 100
    float* tbl  = A0 + 100;                             // 160

    // layer 1: agg(x) @ Wg1^T == agg(x @ Wg1^T)  (aggregate 128 dims, not 200)
    gemm_rows<NFEAT><<<N_NODES / 8, 128, 0, stream>>>(x, Wg1, bufA, N_NODES);
    hipMemsetAsync(bufB, 0, (size_t)N_NODES * 128 * sizeof(float), stream);
    agg_edges<<<2048, 256, 0, stream>>>(ei, ew, bufA, bufB, N_EDGES);
    ln_relu_kernel<<<N_NODES / 4, 256, 0, stream>>>(bufB, bg1, ln1g, ln1b, N_NODES);

    // layer 2
    gemm_rows<NHID><<<N_NODES / 8, 128, 0, stream>>>(bufB, Wg2, bufA, N_NODES);
    hipMemsetAsync(bufB, 0, (size_t)N_NODES * 128 * sizeof(float), stream);
    agg_edges<<<2048, 256, 0, stream>>>(ei, ew, bufA, bufB, N_EDGES);
    ln_relu_kernel<<<N_NODES / 4, 256, 0, stream>>>(bufB, bg2, ln2g, ln2b, N_NODES);
    // bufB = latent [N,128]

    // level 0 pooling
    hipMemsetAsync(xc0, 0, (1280 + 100) * sizeof(float), stream);
    pool0_kernel<<<N_NODES / 4, 256, 0, stream>>>(bufB, p0W, p0b, g0, c0, xc0, N_NODES);
    adj_pool_kernel<<<256, 256, 0, stream>>>(ei, ew, c0, A0, N_EDGES);

    // coarse levels -> tbl
    small_kernel<<<1, 256, 0, stream>>>(xc0, A0, g1, p1W, p1b, e0W, e0b, e1W, e1b,
                                        fcW, fcb, tbl);

    // final: out = latent @ fcA^T + tbl[c0]
    out_kernel<<<N_NODES / 4, 256, 0, stream>>>(bufB, c0, tbl, fcW, out, N_NODES);
}

// Round 2
// 248.870 us; speedup vs baseline: 2.4561x; 2.4561x over previous
//
#include <hip/hip_runtime.h>

#define N_NODES 8192
#define N_EDGES 262144
#define NFEAT 200
#define NHID 128

// ---------------- GEMM: C[nrows,128] = A[nrows,K] @ W[128,K]^T ----------------
template<int K>
__global__ __launch_bounds__(128) void gemm_rows(const float* __restrict__ A,
                                                 const float* __restrict__ W,
                                                 float* __restrict__ C,
                                                 int nrows) {
    __shared__ float a_s[8 * K];
    int row0 = blockIdx.x * 8;
    const float* Ab = A + (size_t)row0 * K;
    for (int idx = threadIdx.x; idx < 8 * K; idx += 128) a_s[idx] = Ab[idx];
    __syncthreads();
    int j = threadIdx.x;
    float acc[8] = {0.f, 0.f, 0.f, 0.f, 0.f, 0.f, 0.f, 0.f};
    const float4* W4 = (const float4*)(W + (size_t)j * K);
    for (int k4 = 0; k4 < K / 4; ++k4) {
        float4 w = W4[k4];
        int k = k4 * 4;
        #pragma unroll
        for (int r = 0; r < 8; ++r) {
            const float* ar = a_s + r * K + k;
            acc[r] += ar[0] * w.x + ar[1] * w.y + ar[2] * w.z + ar[3] * w.w;
        }
    }
    #pragma unroll
    for (int r = 0; r < 8; ++r) C[(size_t)(row0 + r) * 128 + j] = acc[r];
}

// ---------------- CSR build: histogram of dst ----------------
__global__ __launch_bounds__(256) void hist_kernel(const int* __restrict__ ei,
                                                   int* __restrict__ deg, int E) {
    const int* dst = ei + E;
    for (int e = blockIdx.x * blockDim.x + threadIdx.x; e < E; e += gridDim.x * blockDim.x)
        atomicAdd(&deg[dst[e]], 1);
}

// single block, 256 threads: exclusive prefix sum of deg[8192] -> row_start, cursor
__global__ __launch_bounds__(256) void scan_kernel(const int* __restrict__ deg,
                                                   int* __restrict__ row_start,
                                                   int* __restrict__ cursor) {
    __shared__ int part[256];
    __shared__ int partx[257];
    int tid = threadIdx.x;
    int base = tid * 32;
    int s = 0;
    for (int i = 0; i < 32; ++i) s += deg[base + i];
    part[tid] = s;
    __syncthreads();
    if (tid == 0) {
        int run = 0;
        for (int i = 0; i < 256; ++i) { partx[i] = run; run += part[i]; }
        partx[256] = run;
    }
    __syncthreads();
    int run = partx[tid];
    for (int i = 0; i < 32; ++i) {
        row_start[base + i] = run;
        cursor[base + i] = run;
        run += deg[base + i];
    }
    if (tid == 255) row_start[N_NODES] = run;
}

// scatter edges into dst-sorted order
__global__ __launch_bounds__(256) void scatter_kernel(const int* __restrict__ ei,
                                                      const float* __restrict__ ew,
                                                      int* __restrict__ cursor,
                                                      int* __restrict__ ssort,
                                                      float* __restrict__ wsort, int E) {
    int e = blockIdx.x * blockDim.x + threadIdx.x;
    if (e < E) {
        int d = ei[E + e];
        int pos = atomicAdd(&cursor[d], 1);
        ssort[pos] = ei[e];
        wsort[pos] = ew[e];
    }
}

// ---------------- fused: out[i] = relu(LN(sum_{e->i} w_e*H[src_e] + bias)) ----------------
__global__ __launch_bounds__(256) void agg_ln_csr(const int* __restrict__ row_start,
                                                  const int* __restrict__ ssort,
                                                  const float* __restrict__ wsort,
                                                  const float* __restrict__ H,
                                                  float* __restrict__ out,
                                                  const float* __restrict__ bias,
                                                  const float* __restrict__ g,
                                                  const float* __restrict__ b) {
    int wave = (blockIdx.x * blockDim.x + threadIdx.x) >> 6;
    int lane = threadIdx.x & 63;
    int s0 = row_start[wave], s1 = row_start[wave + 1];
    float ax0 = 0.f, ay0 = 0.f, ax1 = 0.f, ay1 = 0.f;
    int e = s0;
    for (; e + 1 < s1; e += 2) {
        int sA = ssort[e], sB = ssort[e + 1];
        float wA = wsort[e], wB = wsort[e + 1];
        float2 vA = *(const float2*)(H + (size_t)sA * 128 + lane * 2);
        float2 vB = *(const float2*)(H + (size_t)sB * 128 + lane * 2);
        ax0 += wA * vA.x; ay0 += wA * vA.y;
        ax1 += wB * vB.x; ay1 += wB * vB.y;
    }
    if (e < s1) {
        int sA = ssort[e];
        float wA = wsort[e];
        float2 vA = *(const float2*)(H + (size_t)sA * 128 + lane * 2);
        ax0 += wA * vA.x; ay0 += wA * vA.y;
    }
    float2 bs = *(const float2*)(bias + lane * 2);
    float vx = ax0 + ax1 + bs.x;
    float vy = ay0 + ay1 + bs.y;
    float s = vx + vy;
    float ss = vx * vx + vy * vy;
    for (int off = 32; off; off >>= 1) {
        s += __shfl_xor(s, off, 64);
        ss += __shfl_xor(ss, off, 64);
    }
    float mu = s * (1.f / 128.f);
    float var = ss * (1.f / 128.f) - mu * mu;
    float rs = rsqrtf(var + 1e-5f);
    float2 gg = *(const float2*)(g + lane * 2);
    float2 bb = *(const float2*)(b + lane * 2);
    float y0 = fmaxf((vx - mu) * rs * gg.x + bb.x, 0.f);
    float y1 = fmaxf((vy - mu) * rs * gg.y + bb.y, 0.f);
    *(float2*)(out + (size_t)wave * 128 + lane * 2) = make_float2(y0, y1);
}

// ---------------- pool0: logits + gumbel argmax -> c0, and xc0 cluster sums ----------------
__global__ __launch_bounds__(256) void pool0_kernel(const float* __restrict__ latent,
                                                    const float* __restrict__ pW,
                                                    const float* __restrict__ pb,
                                                    const float* __restrict__ gum,
                                                    int* __restrict__ c0,
                                                    float* __restrict__ xc0,
                                                    int nrows) {
    __shared__ float Ws[10 * 128];
    __shared__ float bs[10];
    for (int i = threadIdx.x; i < 1280; i += 256) Ws[i] = pW[i];
    if (threadIdx.x < 10) bs[threadIdx.x] = pb[threadIdx.x];
    __syncthreads();
    int wid = threadIdx.x >> 6, lane = threadIdx.x & 63;
    int row = blockIdx.x * 4 + wid;
    if (row >= nrows) return;
    float2 x = *(const float2*)(latent + (size_t)row * 128 + lane * 2);
    float p[10];
    #pragma unroll
    for (int k = 0; k < 10; ++k)
        p[k] = x.x * Ws[k * 128 + lane * 2] + x.y * Ws[k * 128 + lane * 2 + 1];
    for (int off = 32; off; off >>= 1) {
        #pragma unroll
        for (int k = 0; k < 10; ++k) p[k] += __shfl_xor(p[k], off, 64);
    }
    int best = 0;
    float bv = p[0] + bs[0] + gum[row * 10];
    #pragma unroll
    for (int k = 1; k < 10; ++k) {
        float z = p[k] + bs[k] + gum[row * 10 + k];
        if (z > bv) { bv = z; best = k; }   // strict > : first max wins (jnp.argmax)
    }
    if (lane == 0) c0[row] = best;
    atomicAdd(&xc0[best * 128 + lane * 2], x.x);
    atomicAdd(&xc0[best * 128 + lane * 2 + 1], x.y);
}

// ---------------- A0[a,b] = sum_e w_e [c0[src]=a][c0[dst]=b] ----------------
__global__ __launch_bounds__(256) void adj_pool_kernel(const int* __restrict__ ei,
                                                       const float* __restrict__ ew,
                                                       const int* __restrict__ c0,
                                                       float* __restrict__ A0, int E) {
    __shared__ float As[100];
    for (int i = threadIdx.x; i < 100; i += 256) As[i] = 0.f;
    __syncthreads();
    const int* src = ei;
    const int* dst = ei + E;
    for (int e = blockIdx.x * blockDim.x + threadIdx.x; e < E; e += gridDim.x * blockDim.x) {
        int a = c0[src[e]], b = c0[dst[e]];
        atomicAdd(&As[a * 10 + b], ew[e]);
    }
    __syncthreads();
    for (int i = threadIdx.x; i < 100; i += 256) atomicAdd(&A0[i], As[i]);
}

// ---------------- single-block: levels 0/1 coarse math -> tbl[10][16] ----------------
__global__ __launch_bounds__(256) void small_kernel(const float* __restrict__ xc0,
                                                    const float* __restrict__ A0,
                                                    const float* __restrict__ gum1,
                                                    const float* __restrict__ p1W,
                                                    const float* __restrict__ p1b,
                                                    const float* __restrict__ e0W,
                                                    const float* __restrict__ e0b,
                                                    const float* __restrict__ e1W,
                                                    const float* __restrict__ e1b,
                                                    const float* __restrict__ fcW,
                                                    const float* __restrict__ fcb,
                                                    float* __restrict__ tbl) {
    __shared__ float xc0n[10 * 128];
    __shared__ float adj0[100];
    __shared__ float m0[10 * 128];
    __shared__ float l1[10 * 128];
    __shared__ float xc1n[5 * 128];
    __shared__ float l2[5 * 128];
    __shared__ float A1[25];
    __shared__ int c1[10];
    __shared__ float red[4];

    int tid = threadIdx.x;
    int wid = tid >> 6, lane = tid & 63;

    // xc0 row-normalize
    for (int r = wid; r < 10; r += 4) {
        float2 v = *(const float2*)(xc0 + r * 128 + lane * 2);
        float ss = v.x * v.x + v.y * v.y;
        for (int off = 32; off; off >>= 1) ss += __shfl_xor(ss, off, 64);
        float sc = 1.f / fmaxf(sqrtf(ss), 1e-12f);
        xc0n[r * 128 + lane * 2] = v.x * sc;
        xc0n[r * 128 + lane * 2 + 1] = v.y * sc;
    }
    __syncthreads();
    // adj0 = A0 / (sum(A0) + 100*1e-8)
    if (tid == 0) {
        float s = 0.f;
        for (int i = 0; i < 100; ++i) s += A0[i];
        red[0] = s + 1e-6f;
    }
    __syncthreads();
    if (tid < 100) adj0[tid] = A0[tid] / red[0];
    __syncthreads();
    // m0 = adj0 @ xc0n
    for (int idx = tid; idx < 1280; idx += 256) {
        int r = idx >> 7, d = idx & 127;
        float acc = 0.f;
        #pragma unroll
        for (int a = 0; a < 10; ++a) acc += adj0[r * 10 + a] * xc0n[a * 128 + d];
        m0[idx] = acc;
    }
    __syncthreads();
    // l1 = relu(m0 @ e0W^T + e0b)
    for (int idx = tid; idx < 1280; idx += 256) {
        int r = idx >> 7, d = idx & 127;
        float acc = e0b[d];
        const float* wrow = e0W + d * 128;
        for (int k = 0; k < 128; ++k) acc += m0[r * 128 + k] * wrow[k];
        l1[idx] = fmaxf(acc, 0.f);
    }
    __syncthreads();
    // logits1 + gumbel1 argmax -> c1
    if (tid < 10) {
        int best = 0;
        float bv = -1e30f;
        for (int j = 0; j < 5; ++j) {
            float acc = p1b[j] + gum1[tid * 5 + j];
            const float* wrow = p1W + j * 128;
            for (int k = 0; k < 128; ++k) acc += l1[tid * 128 + k] * wrow[k];
            if (acc > bv) { bv = acc; best = j; }
        }
        c1[tid] = best;
    }
    __syncthreads();
    // xc1 = segsum(l1 by c1)
    for (int idx = tid; idx < 640; idx += 256) {
        int m = idx >> 7, d = idx & 127;
        float acc = 0.f;
        #pragma unroll
        for (int k = 0; k < 10; ++k)
            if (c1[k] == m) acc += l1[k * 128 + d];
        xc1n[idx] = acc;
    }
    __syncthreads();
    // normalize rows of xc1
    for (int r = wid; r < 5; r += 4) {
        float2 v = *(const float2*)(xc1n + r * 128 + lane * 2);
        float ss = v.x * v.x + v.y * v.y;
        for (int off = 32; off; off >>= 1) ss += __shfl_xor(ss, off, 64);
        float sc = 1.f / fmaxf(sqrtf(ss), 1e-12f);
        xc1n[r * 128 + lane * 2] = v.x * sc;
        xc1n[r * 128 + lane * 2 + 1] = v.y * sc;
    }
    __syncthreads();
    // A1[m,n] = sum_{a,b} adj0[a,b][c1[a]=m][c1[b]=n]
    if (tid < 25) {
        int m = tid / 5, n = tid % 5;
        float acc = 0.f;
        for (int a = 0; a < 10; ++a)
            for (int b = 0; b < 10; ++b)
                if (c1[a] == m && c1[b] == n) acc += adj0[a * 10 + b];
        A1[tid] = acc;
    }
    __syncthreads();
    if (tid == 0) {
        float s = 0.f;
        for (int i = 0; i < 25; ++i) s += A1[i];
        red[1] = s + 25e-8f;
    }
    __syncthreads();
    float den1 = red[1];
    // m1 = (A1/den1) @ xc1n   (reuse m0)
    for (int idx = tid; idx < 640; idx += 256) {
        int r = idx >> 7, d = idx & 127;
        float acc = 0.f;
        #pragma unroll
        for (int a = 0; a < 5; ++a) acc += A1[r * 5 + a] * xc1n[a * 128 + d];
        m0[idx] = acc / den1;
    }
    __syncthreads();
    // l2 = relu(m1 @ e1W^T + e1b)
    for (int idx = tid; idx < 640; idx += 256) {
        int r = idx >> 7, d = idx & 127;
        float acc = e1b[d];
        const float* wrow = e1W + d * 128;
        for (int k = 0; k < 128; ++k) acc += m0[r * 128 + k] * wrow[k];
        l2[idx] = fmaxf(acc, 0.f);
    }
    __syncthreads();
    // tbl[k][o] = fcb[o] + l1[k]·fcW[o,128:256] + l2[c1[k]]·fcW[o,256:384]
    for (int idx = tid; idx < 160; idx += 256) {
        int k = idx >> 4, o = idx & 15;
        float acc = fcb[o];
        const float* fB = fcW + o * 384 + 128;
        const float* fC = fcW + o * 384 + 256;
        const float* a1 = l1 + k * 128;
        const float* a2 = l2 + c1[k] * 128;
        for (int d = 0; d < 128; ++d) acc += a1[d] * fB[d] + a2[d] * fC[d];
        tbl[idx] = acc;
    }
}

// ---------------- out[i] = latent[i] @ fcA^T + tbl[c0[i]] ----------------
__global__ __launch_bounds__(256) void out_kernel(const float* __restrict__ latent,
                                                  const int* __restrict__ c0,
                                                  const float* __restrict__ tbl,
                                                  const float* __restrict__ fcW,
                                                  float* __restrict__ out, int nrows) {
    __shared__ float fA[16 * 128];
    __shared__ float ts[160];
    for (int i = threadIdx.x; i < 2048; i += 256) {
        int o = i >> 7, d = i & 127;
        fA[i] = fcW[o * 384 + d];
    }
    for (int i = threadIdx.x; i < 160; i += 256) ts[i] = tbl[i];
    __syncthreads();
    int wid = threadIdx.x >> 6, lane = threadIdx.x & 63;
    int row = blockIdx.x * 4 + wid;
    if (row >= nrows) return;
    float2 x = *(const float2*)(latent + (size_t)row * 128 + lane * 2);
    float p[16];
    #pragma unroll
    for (int o = 0; o < 16; ++o)
        p[o] = x.x * fA[o * 128 + lane * 2] + x.y * fA[o * 128 + lane * 2 + 1];
    for (int off = 32; off; off >>= 1) {
        #pragma unroll
        for (int o = 0; o < 16; ++o) p[o] += __shfl_xor(p[o], off, 64);
    }
    if (lane < 16) {
        int c = c0[row];
        out[(size_t)row * 16 + lane] = p[lane] + ts[c * 16 + lane];
    }
}

extern "C" void kernel_launch(void* const* d_in, const int* in_sizes, int n_in,
                              void* d_out, int out_size, void* d_ws, size_t ws_size,
                              hipStream_t stream) {
    const float* x    = (const float*)d_in[0];
    const int*   ei   = (const int*)d_in[1];
    const float* ew   = (const float*)d_in[2];
    const float* g0   = (const float*)d_in[3];
    const float* g1   = (const float*)d_in[4];
    const float* Wg1  = (const float*)d_in[5];
    const float* bg1  = (const float*)d_in[6];
    const float* ln1g = (const float*)d_in[7];
    const float* ln1b = (const float*)d_in[8];
    const float* Wg2  = (const float*)d_in[9];
    const float* bg2  = (const float*)d_in[10];
    const float* ln2g = (const float*)d_in[11];
    const float* ln2b = (const float*)d_in[12];
    const float* p0W  = (const float*)d_in[13];
    const float* p0b  = (const float*)d_in[14];
    const float* p1W  = (const float*)d_in[15];
    const float* p1b  = (const float*)d_in[16];
    const float* e0W  = (const float*)d_in[17];
    const float* e0b  = (const float*)d_in[18];
    const float* e1W  = (const float*)d_in[19];
    const float* e1b  = (const float*)d_in[20];
    const float* fcW  = (const float*)d_in[21];
    const float* fcb  = (const float*)d_in[22];
    float* out = (float*)d_out;

    float* ws   = (float*)d_ws;
    float* bufA = ws;                                        // N*128 f
    float* bufB = bufA + (size_t)N_NODES * 128;              // N*128 f
    int*   c0   = (int*)(bufB + (size_t)N_NODES * 128);      // N int
    float* xc0  = (float*)(c0 + N_NODES);                    // 1280 f
    float* A0   = xc0 + 1280;                                // 100 f
    float* tbl  = A0 + 100;                                  // 160 f
    int*   deg  = (int*)(tbl + 160);                         // N int
    int*   row_start = deg + N_NODES;                        // N+1 int
    int*   cursor    = row_start + N_NODES + 1;              // N int
    int*   ssort     = cursor + N_NODES;                     // E int
    float* wsort     = (float*)(ssort + N_EDGES);            // E f

    // ---- build CSR (dst-sorted edges), reused by both layers ----
    hipMemsetAsync(deg, 0, N_NODES * sizeof(int), stream);
    hist_kernel<<<256, 256, 0, stream>>>(ei, deg, N_EDGES);
    scan_kernel<<<1, 256, 0, stream>>>(deg, row_start, cursor);
    scatter_kernel<<<N_EDGES / 256, 256, 0, stream>>>(ei, ew, cursor, ssort, wsort, N_EDGES);

    // layer 1: agg(x) @ Wg1^T == agg(x @ Wg1^T); then fused +bias, LN, relu
    gemm_rows<NFEAT><<<N_NODES / 8, 128, 0, stream>>>(x, Wg1, bufA, N_NODES);
    agg_ln_csr<<<N_NODES / 4, 256, 0, stream>>>(row_start, ssort, wsort, bufA, bufB,
                                                bg1, ln1g, ln1b);

    // layer 2
    gemm_rows<NHID><<<N_NODES / 8, 128, 0, stream>>>(bufB, Wg2, bufA, N_NODES);
    agg_ln_csr<<<N_NODES / 4, 256, 0, stream>>>(row_start, ssort, wsort, bufA, bufB,
                                                bg2, ln2g, ln2b);
    // bufB = latent [N,128]

    // level 0 pooling
    hipMemsetAsync(xc0, 0, (1280 + 100) * sizeof(float), stream);
    pool0_kernel<<<N_NODES / 4, 256, 0, stream>>>(bufB, p0W, p0b, g0, c0, xc0, N_NODES);
    adj_pool_kernel<<<256, 256, 0, stream>>>(ei, ew, c0, A0, N_EDGES);

    // coarse levels -> tbl
    small_kernel<<<1, 256, 0, stream>>>(xc0, A0, g1, p1W, p1b, e0W, e0b, e1W, e1b,
                                        fcW, fcb, tbl);

    // final: out = latent @ fcA^T + tbl[c0]
    out_kernel<<<N_NODES / 4, 256, 0, stream>>>(bufB, c0, tbl, fcW, out, N_NODES);
}

// Round 3
// 227.667 us; speedup vs baseline: 2.6848x; 1.0931x over previous
//
#include <hip/hip_runtime.h>

#define N_NODES 8192
#define N_EDGES 262144
#define NFEAT 200
#define NHID 128

// ---------------- GEMM: C[nrows,128] = A[nrows,K] @ W[128,K]^T ----------------
template<int K>
__global__ __launch_bounds__(128) void gemm_rows(const float* __restrict__ A,
                                                 const float* __restrict__ W,
                                                 float* __restrict__ C,
                                                 int nrows) {
    __shared__ float a_s[8 * K];
    int row0 = blockIdx.x * 8;
    const float* Ab = A + (size_t)row0 * K;
    for (int idx = threadIdx.x; idx < 8 * K; idx += 128) a_s[idx] = Ab[idx];
    __syncthreads();
    int j = threadIdx.x;
    float acc[8] = {0.f, 0.f, 0.f, 0.f, 0.f, 0.f, 0.f, 0.f};
    const float4* W4 = (const float4*)(W + (size_t)j * K);
    for (int k4 = 0; k4 < K / 4; ++k4) {
        float4 w = W4[k4];
        int k = k4 * 4;
        #pragma unroll
        for (int r = 0; r < 8; ++r) {
            const float* ar = a_s + r * K + k;
            acc[r] += ar[0] * w.x + ar[1] * w.y + ar[2] * w.z + ar[3] * w.w;
        }
    }
    #pragma unroll
    for (int r = 0; r < 8; ++r) C[(size_t)(row0 + r) * 128 + j] = acc[r];
}

// ---------------- CSR build: histogram of dst ----------------
__global__ __launch_bounds__(256) void hist_kernel(const int* __restrict__ ei,
                                                   int* __restrict__ deg, int E) {
    const int* dst = ei + E;
    for (int e = blockIdx.x * blockDim.x + threadIdx.x; e < E; e += gridDim.x * blockDim.x)
        atomicAdd(&deg[dst[e]], 1);
}

// single block, 256 threads: exclusive prefix sum of deg[8192] -> row_start, cursor
__global__ __launch_bounds__(256) void scan_kernel(const int* __restrict__ deg,
                                                   int* __restrict__ row_start,
                                                   int* __restrict__ cursor) {
    __shared__ int part[256];
    __shared__ int partx[257];
    int tid = threadIdx.x;
    int base = tid * 32;
    int s = 0;
    for (int i = 0; i < 32; ++i) s += deg[base + i];
    part[tid] = s;
    __syncthreads();
    if (tid == 0) {
        int run = 0;
        for (int i = 0; i < 256; ++i) { partx[i] = run; run += part[i]; }
        partx[256] = run;
    }
    __syncthreads();
    int run = partx[tid];
    for (int i = 0; i < 32; ++i) {
        row_start[base + i] = run;
        cursor[base + i] = run;
        run += deg[base + i];
    }
    if (tid == 255) row_start[N_NODES] = run;
}

// scatter edges into dst-sorted order
__global__ __launch_bounds__(256) void scatter_kernel(const int* __restrict__ ei,
                                                      const float* __restrict__ ew,
                                                      int* __restrict__ cursor,
                                                      int* __restrict__ ssort,
                                                      float* __restrict__ wsort, int E) {
    int e = blockIdx.x * blockDim.x + threadIdx.x;
    if (e < E) {
        int d = ei[E + e];
        int pos = atomicAdd(&cursor[d], 1);
        ssort[pos] = ei[e];
        wsort[pos] = ew[e];
    }
}

// ---------------- fused: out[i] = relu(LN(sum_{e->i} w_e*H[src_e] + bias)) ----------------
__global__ __launch_bounds__(256) void agg_ln_csr(const int* __restrict__ row_start,
                                                  const int* __restrict__ ssort,
                                                  const float* __restrict__ wsort,
                                                  const float* __restrict__ H,
                                                  float* __restrict__ out,
                                                  const float* __restrict__ bias,
                                                  const float* __restrict__ g,
                                                  const float* __restrict__ b) {
    int wave = (blockIdx.x * blockDim.x + threadIdx.x) >> 6;
    int lane = threadIdx.x & 63;
    int s0 = row_start[wave], s1 = row_start[wave + 1];
    float ax0 = 0.f, ay0 = 0.f, ax1 = 0.f, ay1 = 0.f;
    int e = s0;
    for (; e + 1 < s1; e += 2) {
        int sA = ssort[e], sB = ssort[e + 1];
        float wA = wsort[e], wB = wsort[e + 1];
        float2 vA = *(const float2*)(H + (size_t)sA * 128 + lane * 2);
        float2 vB = *(const float2*)(H + (size_t)sB * 128 + lane * 2);
        ax0 += wA * vA.x; ay0 += wA * vA.y;
        ax1 += wB * vB.x; ay1 += wB * vB.y;
    }
    if (e < s1) {
        int sA = ssort[e];
        float wA = wsort[e];
        float2 vA = *(const float2*)(H + (size_t)sA * 128 + lane * 2);
        ax0 += wA * vA.x; ay0 += wA * vA.y;
    }
    float2 bs = *(const float2*)(bias + lane * 2);
    float vx = ax0 + ax1 + bs.x;
    float vy = ay0 + ay1 + bs.y;
    float s = vx + vy;
    float ss = vx * vx + vy * vy;
    for (int off = 32; off; off >>= 1) {
        s += __shfl_xor(s, off, 64);
        ss += __shfl_xor(ss, off, 64);
    }
    float mu = s * (1.f / 128.f);
    float var = ss * (1.f / 128.f) - mu * mu;
    float rs = rsqrtf(var + 1e-5f);
    float2 gg = *(const float2*)(g + lane * 2);
    float2 bb = *(const float2*)(b + lane * 2);
    float y0 = fmaxf((vx - mu) * rs * gg.x + bb.x, 0.f);
    float y1 = fmaxf((vy - mu) * rs * gg.y + bb.y, 0.f);
    *(float2*)(out + (size_t)wave * 128 + lane * 2) = make_float2(y0, y1);
}

// ---------------- pool0: logits + gumbel argmax -> c0, LDS-privatized xc0 sums ----------------
__global__ __launch_bounds__(256) void pool0_kernel(const float* __restrict__ latent,
                                                    const float* __restrict__ pW,
                                                    const float* __restrict__ pb,
                                                    const float* __restrict__ gum,
                                                    int* __restrict__ c0,
                                                    float* __restrict__ xc0,
                                                    int nrows) {
    __shared__ float Ws[10 * 128];
    __shared__ float bs[10];
    __shared__ float acc[10 * 128];
    for (int i = threadIdx.x; i < 1280; i += 256) { Ws[i] = pW[i]; acc[i] = 0.f; }
    if (threadIdx.x < 10) bs[threadIdx.x] = pb[threadIdx.x];
    __syncthreads();
    int wid = threadIdx.x >> 6, lane = threadIdx.x & 63;
    for (int row = blockIdx.x * 4 + wid; row < nrows; row += gridDim.x * 4) {
        float2 x = *(const float2*)(latent + (size_t)row * 128 + lane * 2);
        float p[10];
        #pragma unroll
        for (int k = 0; k < 10; ++k)
            p[k] = x.x * Ws[k * 128 + lane * 2] + x.y * Ws[k * 128 + lane * 2 + 1];
        for (int off = 32; off; off >>= 1) {
            #pragma unroll
            for (int k = 0; k < 10; ++k) p[k] += __shfl_xor(p[k], off, 64);
        }
        int best = 0;
        float bv = p[0] + bs[0] + gum[row * 10];
        #pragma unroll
        for (int k = 1; k < 10; ++k) {
            float z = p[k] + bs[k] + gum[row * 10 + k];
            if (z > bv) { bv = z; best = k; }   // strict > : first max wins (jnp.argmax)
        }
        if (lane == 0) c0[row] = best;
        atomicAdd(&acc[best * 128 + lane * 2], x.x);
        atomicAdd(&acc[best * 128 + lane * 2 + 1], x.y);
    }
    __syncthreads();
    for (int i = threadIdx.x; i < 1280; i += 256) atomicAdd(&xc0[i], acc[i]);
}

// ---------------- A0[a,b] = sum_e w_e [c0[src]=a][c0[dst]=b] ----------------
__global__ __launch_bounds__(256) void adj_pool_kernel(const int* __restrict__ ei,
                                                       const float* __restrict__ ew,
                                                       const int* __restrict__ c0,
                                                       float* __restrict__ A0, int E) {
    __shared__ float As[100];
    for (int i = threadIdx.x; i < 100; i += 256) As[i] = 0.f;
    __syncthreads();
    const int* src = ei;
    const int* dst = ei + E;
    for (int e = blockIdx.x * blockDim.x + threadIdx.x; e < E; e += gridDim.x * blockDim.x) {
        int a = c0[src[e]], b = c0[dst[e]];
        atomicAdd(&As[a * 10 + b], ew[e]);
    }
    __syncthreads();
    for (int i = threadIdx.x; i < 100; i += 256) atomicAdd(&A0[i], As[i]);
}

// ---------------- single-block: levels 0/1 coarse math -> tbl[10][16] ----------------
__global__ __launch_bounds__(256) void small_kernel(const float* __restrict__ xc0,
                                                    const float* __restrict__ A0,
                                                    const float* __restrict__ gum1,
                                                    const float* __restrict__ p1W,
                                                    const float* __restrict__ p1b,
                                                    const float* __restrict__ e0W,
                                                    const float* __restrict__ e0b,
                                                    const float* __restrict__ e1W,
                                                    const float* __restrict__ e1b,
                                                    const float* __restrict__ fcW,
                                                    const float* __restrict__ fcb,
                                                    float* __restrict__ tbl) {
    __shared__ float xc0n[10 * 128];
    __shared__ float adj0[100];
    __shared__ float m0[10 * 128];
    __shared__ float l1[10 * 128];
    __shared__ float xc1n[5 * 128];
    __shared__ float l2[5 * 128];
    __shared__ float A1[25];
    __shared__ int c1[10];
    __shared__ float red[4];

    int tid = threadIdx.x;
    int wid = tid >> 6, lane = tid & 63;

    // xc0 row-normalize
    for (int r = wid; r < 10; r += 4) {
        float2 v = *(const float2*)(xc0 + r * 128 + lane * 2);
        float ss = v.x * v.x + v.y * v.y;
        for (int off = 32; off; off >>= 1) ss += __shfl_xor(ss, off, 64);
        float sc = 1.f / fmaxf(sqrtf(ss), 1e-12f);
        xc0n[r * 128 + lane * 2] = v.x * sc;
        xc0n[r * 128 + lane * 2 + 1] = v.y * sc;
    }
    __syncthreads();
    // adj0 = A0 / (sum(A0) + 100*1e-8)
    if (tid == 0) {
        float s = 0.f;
        for (int i = 0; i < 100; ++i) s += A0[i];
        red[0] = s + 1e-6f;
    }
    __syncthreads();
    if (tid < 100) adj0[tid] = A0[tid] / red[0];
    __syncthreads();
    // m0 = adj0 @ xc0n
    for (int idx = tid; idx < 1280; idx += 256) {
        int r = idx >> 7, d = idx & 127;
        float acc = 0.f;
        #pragma unroll
        for (int a = 0; a < 10; ++a) acc += adj0[r * 10 + a] * xc0n[a * 128 + d];
        m0[idx] = acc;
    }
    __syncthreads();
    // l1 = relu(m0 @ e0W^T + e0b)
    for (int idx = tid; idx < 1280; idx += 256) {
        int r = idx >> 7, d = idx & 127;
        float acc = e0b[d];
        const float* wrow = e0W + d * 128;
        for (int k = 0; k < 128; ++k) acc += m0[r * 128 + k] * wrow[k];
        l1[idx] = fmaxf(acc, 0.f);
    }
    __syncthreads();
    // logits1 + gumbel1 argmax -> c1
    if (tid < 10) {
        int best = 0;
        float bv = -1e30f;
        for (int j = 0; j < 5; ++j) {
            float acc = p1b[j] + gum1[tid * 5 + j];
            const float* wrow = p1W + j * 128;
            for (int k = 0; k < 128; ++k) acc += l1[tid * 128 + k] * wrow[k];
            if (acc > bv) { bv = acc; best = j; }
        }
        c1[tid] = best;
    }
    __syncthreads();
    // xc1 = segsum(l1 by c1)
    for (int idx = tid; idx < 640; idx += 256) {
        int m = idx >> 7, d = idx & 127;
        float acc = 0.f;
        #pragma unroll
        for (int k = 0; k < 10; ++k)
            if (c1[k] == m) acc += l1[k * 128 + d];
        xc1n[idx] = acc;
    }
    __syncthreads();
    // normalize rows of xc1
    for (int r = wid; r < 5; r += 4) {
        float2 v = *(const float2*)(xc1n + r * 128 + lane * 2);
        float ss = v.x * v.x + v.y * v.y;
        for (int off = 32; off; off >>= 1) ss += __shfl_xor(ss, off, 64);
        float sc = 1.f / fmaxf(sqrtf(ss), 1e-12f);
        xc1n[r * 128 + lane * 2] = v.x * sc;
        xc1n[r * 128 + lane * 2 + 1] = v.y * sc;
    }
    __syncthreads();
    // A1[m,n] = sum_{a,b} adj0[a,b][c1[a]=m][c1[b]=n]
    if (tid < 25) {
        int m = tid / 5, n = tid % 5;
        float acc = 0.f;
        for (int a = 0; a < 10; ++a)
            for (int b = 0; b < 10; ++b)
                if (c1[a] == m && c1[b] == n) acc += adj0[a * 10 + b];
        A1[tid] = acc;
    }
    __syncthreads();
    if (tid == 0) {
        float s = 0.f;
        for (int i = 0; i < 25; ++i) s += A1[i];
        red[1] = s + 25e-8f;
    }
    __syncthreads();
    float den1 = red[1];
    // m1 = (A1/den1) @ xc1n   (reuse m0)
    for (int idx = tid; idx < 640; idx += 256) {
        int r = idx >> 7, d = idx & 127;
        float acc = 0.f;
        #pragma unroll
        for (int a = 0; a < 5; ++a) acc += A1[r * 5 + a] * xc1n[a * 128 + d];
        m0[idx] = acc / den1;
    }
    __syncthreads();
    // l2 = relu(m1 @ e1W^T + e1b)
    for (int idx = tid; idx < 640; idx += 256) {
        int r = idx >> 7, d = idx & 127;
        float acc = e1b[d];
        const float* wrow = e1W + d * 128;
        for (int k = 0; k < 128; ++k) acc += m0[r * 128 + k] * wrow[k];
        l2[idx] = fmaxf(acc, 0.f);
    }
    __syncthreads();
    // tbl[k][o] = fcb[o] + l1[k]·fcW[o,128:256] + l2[c1[k]]·fcW[o,256:384]
    for (int idx = tid; idx < 160; idx += 256) {
        int k = idx >> 4, o = idx & 15;
        float acc = fcb[o];
        const float* fB = fcW + o * 384 + 128;
        const float* fC = fcW + o * 384 + 256;
        const float* a1 = l1 + k * 128;
        const float* a2 = l2 + c1[k] * 128;
        for (int d = 0; d < 128; ++d) acc += a1[d] * fB[d] + a2[d] * fC[d];
        tbl[idx] = acc;
    }
}

// ---------------- out[i] = latent[i] @ fcA^T + tbl[c0[i]] ----------------
__global__ __launch_bounds__(256) void out_kernel(const float* __restrict__ latent,
                                                  const int* __restrict__ c0,
                                                  const float* __restrict__ tbl,
                                                  const float* __restrict__ fcW,
                                                  float* __restrict__ out, int nrows) {
    __shared__ float fA[16 * 128];
    __shared__ float ts[160];
    for (int i = threadIdx.x; i < 2048; i += 256) {
        int o = i >> 7, d = i & 127;
        fA[i] = fcW[o * 384 + d];
    }
    for (int i = threadIdx.x; i < 160; i += 256) ts[i] = tbl[i];
    __syncthreads();
    int wid = threadIdx.x >> 6, lane = threadIdx.x & 63;
    int row = blockIdx.x * 4 + wid;
    if (row >= nrows) return;
    float2 x = *(const float2*)(latent + (size_t)row * 128 + lane * 2);
    float p[16];
    #pragma unroll
    for (int o = 0; o < 16; ++o)
        p[o] = x.x * fA[o * 128 + lane * 2] + x.y * fA[o * 128 + lane * 2 + 1];
    for (int off = 32; off; off >>= 1) {
        #pragma unroll
        for (int o = 0; o < 16; ++o) p[o] += __shfl_xor(p[o], off, 64);
    }
    if (lane < 16) {
        int c = c0[row];
        out[(size_t)row * 16 + lane] = p[lane] + ts[c * 16 + lane];
    }
}

extern "C" void kernel_launch(void* const* d_in, const int* in_sizes, int n_in,
                              void* d_out, int out_size, void* d_ws, size_t ws_size,
                              hipStream_t stream) {
    const float* x    = (const float*)d_in[0];
    const int*   ei   = (const int*)d_in[1];
    const float* ew   = (const float*)d_in[2];
    const float* g0   = (const float*)d_in[3];
    const float* g1   = (const float*)d_in[4];
    const float* Wg1  = (const float*)d_in[5];
    const float* bg1  = (const float*)d_in[6];
    const float* ln1g = (const float*)d_in[7];
    const float* ln1b = (const float*)d_in[8];
    const float* Wg2  = (const float*)d_in[9];
    const float* bg2  = (const float*)d_in[10];
    const float* ln2g = (const float*)d_in[11];
    const float* ln2b = (const float*)d_in[12];
    const float* p0W  = (const float*)d_in[13];
    const float* p0b  = (const float*)d_in[14];
    const float* p1W  = (const float*)d_in[15];
    const float* p1b  = (const float*)d_in[16];
    const float* e0W  = (const float*)d_in[17];
    const float* e0b  = (const float*)d_in[18];
    const float* e1W  = (const float*)d_in[19];
    const float* e1b  = (const float*)d_in[20];
    const float* fcW  = (const float*)d_in[21];
    const float* fcb  = (const float*)d_in[22];
    float* out = (float*)d_out;

    float* ws   = (float*)d_ws;
    float* bufA = ws;                                        // N*128 f
    float* bufB = bufA + (size_t)N_NODES * 128;              // N*128 f
    int*   c0   = (int*)(bufB + (size_t)N_NODES * 128);      // N int
    float* xc0  = (float*)(c0 + N_NODES);                    // 1280 f
    float* A0   = xc0 + 1280;                                // 100 f
    float* tbl  = A0 + 100;                                  // 160 f
    int*   deg  = (int*)(tbl + 160);                         // N int
    int*   row_start = deg + N_NODES;                        // N+1 int
    int*   cursor    = row_start + N_NODES + 1;              // N int
    int*   ssort     = cursor + N_NODES;                     // E int
    float* wsort     = (float*)(ssort + N_EDGES);            // E f

    // ---- build CSR (dst-sorted edges), reused by both layers ----
    hipMemsetAsync(deg, 0, N_NODES * sizeof(int), stream);
    hist_kernel<<<256, 256, 0, stream>>>(ei, deg, N_EDGES);
    scan_kernel<<<1, 256, 0, stream>>>(deg, row_start, cursor);
    scatter_kernel<<<N_EDGES / 256, 256, 0, stream>>>(ei, ew, cursor, ssort, wsort, N_EDGES);

    // layer 1: agg(x) @ Wg1^T == agg(x @ Wg1^T); then fused +bias, LN, relu
    gemm_rows<NFEAT><<<N_NODES / 8, 128, 0, stream>>>(x, Wg1, bufA, N_NODES);
    agg_ln_csr<<<N_NODES / 4, 256, 0, stream>>>(row_start, ssort, wsort, bufA, bufB,
                                                bg1, ln1g, ln1b);

    // layer 2
    gemm_rows<NHID><<<N_NODES / 8, 128, 0, stream>>>(bufB, Wg2, bufA, N_NODES);
    agg_ln_csr<<<N_NODES / 4, 256, 0, stream>>>(row_start, ssort, wsort, bufA, bufB,
                                                bg2, ln2g, ln2b);
    // bufB = latent [N,128]

    // level 0 pooling (LDS-privatized xc0)
    hipMemsetAsync(xc0, 0, (1280 + 100) * sizeof(float), stream);
    pool0_kernel<<<128, 256, 0, stream>>>(bufB, p0W, p0b, g0, c0, xc0, N_NODES);
    adj_pool_kernel<<<256, 256, 0, stream>>>(ei, ew, c0, A0, N_EDGES);

    // coarse levels -> tbl
    small_kernel<<<1, 256, 0, stream>>>(xc0, A0, g1, p1W, p1b, e0W, e0b, e1W, e1b,
                                        fcW, fcb, tbl);

    // final: out = latent @ fcA^T + tbl[c0]
    out_kernel<<<N_NODES / 4, 256, 0, stream>>>(bufB, c0, tbl, fcW, out, N_NODES);
}